// Round 5
// baseline (343.658 us; speedup 1.0000x reference)
//
#include <hip/hip_runtime.h>
#include <hip/hip_bf16.h>

typedef __hip_bfloat16 bf16;
typedef unsigned int uint;

using frag8 = __attribute__((ext_vector_type(8))) short;   // 8 bf16
using f32x4 = __attribute__((ext_vector_type(4))) float;

#define HWH 784    // 28*28
#define KW  2336   // 9 taps * 256 ci + 32-col bias/validity block

// ---------------------------------------------------------------------------
// prep: build A' [256][2336] bf16 folded weights, V validity table [784][32],
// and a 16-B zero buffer (per-launch, since ws is re-poisoned).
//   A'[oc][tap*256+ci] = sum_s (sum_o fc_w[o][s]*dep_w[oc][o][tap]) * wsec(s)[(s&3)*64+oc/4][ci]
//   A'[oc][2304+tap]   = same fold applied to biases (gated by validity channel)
//   V[p][tap]          = 1.0 if conv tap valid at pixel p else 0   (taps 9..31 = 0)
// ---------------------------------------------------------------------------
__global__ __launch_bounds__(256) void prep(const float* __restrict__ fc_w,
                                            const float* __restrict__ dep_w,
                                            const float* __restrict__ w1,
                                            const float* __restrict__ w2,
                                            const float* __restrict__ w3,
                                            const float* __restrict__ b1,
                                            const float* __restrict__ b2,
                                            const float* __restrict__ b3,
                                            bf16* __restrict__ Ap,
                                            bf16* __restrict__ Vt,
                                            bf16* __restrict__ zb) {
    __shared__ float W2v[12];
    const int blk = blockIdx.x, tid = threadIdx.x;
    if (blk < 2304) {                        // main fold: block = (oc, tap)
        int oc = blk / 9, tap = blk % 9, hd = oc >> 2;
        if (tid < 12) {
            float s = 0.f;
            for (int o = 0; o < 9; ++o)
                s += fc_w[o * 12 + tid] * dep_w[oc * 81 + o * 9 + tap];
            W2v[tid] = s;
        }
        __syncthreads();
        float s = 0.f;
        for (int t = 0; t < 12; ++t) {
            const float* wsec = (t < 4) ? w1 : (t < 8 ? w2 : w3);
            s += W2v[t] * wsec[((t & 3) * 64 + hd) * 256 + tid];
        }
        Ap[(size_t)oc * KW + tap * 256 + tid] = __float2bfloat16(s);
    } else if (blk < 2560) {                 // bias columns (32 per oc)
        int oc = blk - 2304, hd = oc >> 2;
        if (tid < 32) {
            float val = 0.f;
            if (tid < 9) {
                for (int t = 0; t < 12; ++t) {
                    float w2v = 0.f;
                    for (int o = 0; o < 9; ++o)
                        w2v += fc_w[o * 12 + t] * dep_w[oc * 81 + o * 9 + tid];
                    const float* bsec = (t < 4) ? b1 : (t < 8 ? b2 : b3);
                    val += w2v * bsec[(t & 3) * 64 + hd];
                }
            }
            Ap[(size_t)oc * KW + 2304 + tid] = __float2bfloat16(val);
        }
    } else {                                 // validity table + zerobuf
        int i = (blk - 2560) * 256 + tid;
        if (i < 25088) {
            int p = i >> 5, j = i & 31;
            float v = 0.f;
            if (j < 9) {
                int dy = j / 3 - 1, dx = j % 3 - 1;
                int y = p / 28, x = p - 28 * (p / 28);
                if ((uint)(y + dy) < 28u && (uint)(x + dx) < 28u) v = 1.f;
            }
            Vt[i] = __float2bfloat16(v);
        } else if (i < 25096) {
            zb[i - 25088] = __float2bfloat16(0.f);
        }
    }
}

// ---------------------------------------------------------------------------
// x [b][c=256][n=784] f32  ->  xT [b][n=784][c=256] bf16  (32x32 LDS tiles)
// ---------------------------------------------------------------------------
__global__ __launch_bounds__(256) void xpose(const float* __restrict__ x,
                                             bf16* __restrict__ xT) {
    __shared__ float t[32][33];
    const int n0 = blockIdx.x * 32, c0 = blockIdx.y * 32, b = blockIdx.z;
    const int tid = threadIdx.x;
    const float* xb = x + (size_t)b * (256 * HWH);
#pragma unroll
    for (int e = tid; e < 1024; e += 256) {
        int r = e >> 5, col = e & 31;
        int n = n0 + col;
        t[r][col] = (n < HWH) ? xb[(size_t)(c0 + r) * HWH + n] : 0.f;
    }
    __syncthreads();
#pragma unroll
    for (int e = tid; e < 512; e += 256) {
        int r = e >> 4, cp = (e & 15) * 2;
        int n = n0 + r;
        if (n < HWH) {
            __hip_bfloat162 h;
            h.x = __float2bfloat16(t[cp][r]);
            h.y = __float2bfloat16(t[cp + 1][r]);
            *reinterpret_cast<__hip_bfloat162*>(
                &xT[((size_t)b * HWH + n) * 256 + c0 + cp]) = h;
        }
    }
}

// ---------------------------------------------------------------------------
// Window means of x (f32, exact): xm[b][ci][w] = mean of 12x12 patch of
// interior window w = (wi-1)*5 + (wj-1).
// ---------------------------------------------------------------------------
__global__ __launch_bounds__(64) void xmk(const float* __restrict__ x,
                                          float* __restrict__ xm) {
    __shared__ float vp[HWH];
    const int ci = blockIdx.x, b = blockIdx.y, tid = threadIdx.x;
    const float* xp = x + (size_t)(b * 256 + ci) * HWH;
    for (int i = tid; i < HWH; i += 64) vp[i] = xp[i];
    __syncthreads();
    if (tid < 25) {
        int r0 = (tid / 5) * 4, c0 = (tid % 5) * 4;
        float s = 0.f;
#pragma unroll
        for (int r = 0; r < 12; ++r)
#pragma unroll
            for (int c = 0; c < 12; ++c)
                s += vp[(r0 + r) * 28 + c0 + c];
        xm[((size_t)b * 256 + ci) * 25 + tid] = s * (1.0f / 144.0f);
    }
}

// ---------------------------------------------------------------------------
// att[b][oc][w] = sum_ci w3[oc][ci] * xm[b][ci][w] + b3[oc]   (f32, exact)
// ---------------------------------------------------------------------------
__global__ __launch_bounds__(256) void attg(const float* __restrict__ xm,
                                            const float* __restrict__ w3,
                                            const float* __restrict__ b3,
                                            float* __restrict__ att) {
    __shared__ float xs[256][25];
    const int b = blockIdx.x, tid = threadIdx.x;
    for (int e = tid; e < 6400; e += 256) xs[e / 25][e % 25] = xm[(size_t)b * 6400 + e];
    __syncthreads();
    float acc[25];
    const float bv = b3[tid];
#pragma unroll
    for (int w = 0; w < 25; ++w) acc[w] = bv;
    for (int ci = 0; ci < 256; ++ci) {
        float wv = w3[tid * 256 + ci];
#pragma unroll
        for (int w = 0; w < 25; ++w) acc[w] += wv * xs[ci][w];
    }
#pragma unroll
    for (int w = 0; w < 25; ++w)
        att[((size_t)b * 256 + tid) * 25 + w] = acc[w];
}

// ---------------------------------------------------------------------------
// Fused conv-GEMM: out[b][oc][p] = rate2 * (A' row oc) . (B' col p) + rate1*att
// B'[p][tap*256+ci] = valid(p,tap) ? xT[b][p+delta(tap)][ci] : 0  (zerobuf ptr)
// B'[p][2304+j]     = V[p][j]  (validity channels -> exact border bias)
// M=256 (2 tiles), N=784 (7 tiles of 128), K=2336 (73 iters of 32).
// 4 waves, each 64x64 (4x4 of 16x16x32 bf16 MFMA), fragment-ordered LDS.
// ---------------------------------------------------------------------------
__device__ inline void load_lds16(const bf16* g, short* lds) {
    __builtin_amdgcn_global_load_lds(
        (const __attribute__((address_space(1))) void*)g,
        (__attribute__((address_space(3))) void*)lds, 16, 0, 0);
}

__global__ __launch_bounds__(256) void convgemm(const bf16* __restrict__ Ap,
                                                const bf16* __restrict__ xT,
                                                const bf16* __restrict__ Vt,
                                                const bf16* __restrict__ zb,
                                                const float* __restrict__ att,
                                                const float* __restrict__ rate1,
                                                const float* __restrict__ rate2,
                                                float* __restrict__ out) {
    __shared__ short lds[8192];              // A: [0,4096) shorts, B: [4096,8192)

    const int tid  = threadIdx.x;
    const int wave = tid >> 6, lane = tid & 63;
    const int b    = blockIdx.z;
    const int m0   = blockIdx.y * 128;
    const int n0   = blockIdx.x * 128;
    const int mw   = wave & 1, nw = wave >> 1;
    const int lrow = lane & 15, lkc = lane >> 4;

    f32x4 acc[4][4] = {};
    const bf16* xb = xT + (size_t)b * (HWH * 256);

    // per-lane B-row constants for the two staged fragment-blocks
    int p_[2], py_[2], px_[2];
#pragma unroll
    for (int i = 0; i < 2; ++i) {
        int p = n0 + 16 * (2 * wave + i) + lrow;
        p_[i] = p; py_[i] = p / 28; px_[i] = p - 28 * (p / 28);
    }

    for (int it = 0; it < 73; ++it) {
        const int kcol = it * 32 + lkc * 8;
#pragma unroll
        for (int i = 0; i < 2; ++i) {
            const int jbv = 2 * wave + i;
            const bf16* ga = Ap + (size_t)(m0 + 16 * jbv + lrow) * KW + kcol;
            load_lds16(ga, &lds[jbv * 512]);
            const bf16* gb;
            if (it < 72) {
                int tap = it >> 3;
                int dy = tap / 3 - 1, dx = tap % 3 - 1;        // wave-uniform
                int kin = (it & 7) * 32;
                bool valid = (p_[i] < HWH) &&
                             ((uint)(py_[i] + dy) < 28u) &&
                             ((uint)(px_[i] + dx) < 28u);
                int q = p_[i] + dy * 28 + dx;
                gb = valid ? (xb + (size_t)q * 256 + kin + lkc * 8)
                           : (const bf16*)zb;
            } else {
                gb = (p_[i] < HWH) ? (Vt + (size_t)p_[i] * 32 + lkc * 8)
                                   : (const bf16*)zb;
            }
            load_lds16(gb, &lds[4096 + jbv * 512]);
        }
        __syncthreads();

        frag8 af[4], bf_[4];
#pragma unroll
        for (int i = 0; i < 4; ++i)
            af[i] = *reinterpret_cast<const frag8*>(&lds[(4 * mw + i) * 512 + lane * 8]);
#pragma unroll
        for (int j = 0; j < 4; ++j)
            bf_[j] = *reinterpret_cast<const frag8*>(&lds[4096 + (4 * nw + j) * 512 + lane * 8]);
#pragma unroll
        for (int i = 0; i < 4; ++i)
#pragma unroll
            for (int j = 0; j < 4; ++j)
                acc[i][j] = __builtin_amdgcn_mfma_f32_16x16x32_bf16(
                    af[i], bf_[j], acc[i][j], 0, 0, 0);
        __syncthreads();
    }

    // Epilogue: C/D col = lane&15 (n=pixel), row = lkc*4+reg (m=channel).
    const float r1 = rate1[0], r2 = rate2[0];
#pragma unroll
    for (int j = 0; j < 4; ++j) {
        const int col = n0 + nw * 64 + j * 16 + lrow;
        if (col < HWH) {
            int cy = col / 28, cx = col - 28 * cy;
            int wi = (cy >> 2) - 1, wj = (cx >> 2) - 1;
            bool inter = ((uint)wi < 5u) && ((uint)wj < 5u);
            int wio = inter ? (wi * 5 + wj) : 0;
#pragma unroll
            for (int i = 0; i < 4; ++i) {
                const int mb = m0 + mw * 64 + i * 16 + lkc * 4;
#pragma unroll
                for (int r = 0; r < 4; ++r) {
                    const int m = mb + r;
                    float av = inter ? att[((size_t)b * 256 + m) * 25 + wio] : 0.f;
                    out[((size_t)b * 256 + m) * HWH + col] =
                        r2 * acc[i][j][r] + r1 * av;
                }
            }
        }
    }
}

// ---------------------------------------------------------------------------
extern "C" void kernel_launch(void* const* d_in, const int* in_sizes, int n_in,
                              void* d_out, int out_size, void* d_ws, size_t ws_size,
                              hipStream_t stream) {
    const float* x     = (const float*)d_in[0];
    const float* w1    = (const float*)d_in[1];
    const float* b1    = (const float*)d_in[2];
    const float* w2    = (const float*)d_in[3];
    const float* b2    = (const float*)d_in[4];
    const float* w3    = (const float*)d_in[5];
    const float* b3    = (const float*)d_in[6];
    const float* fc_w  = (const float*)d_in[7];
    const float* dep_w = (const float*)d_in[8];
    // d_in[9]/d_in[10] = rel_height/rel_width: provably dead (mask collapse)
    const float* rate1 = (const float*)d_in[11];
    const float* rate2 = (const float*)d_in[12];
    float* out = (float*)d_out;

    // workspace layout (bytes, all 16-aligned)
    char* wsb = (char*)d_ws;
    bf16*  xT  = (bf16*)wsb;                        // 64*784*256*2 = 25,690,112
    bf16*  Ap  = (bf16*)(wsb + 25690112);           // 256*2336*2   =  1,196,032
    bf16*  Vt  = (bf16*)(wsb + 26886144);           // 784*32*2     =     50,176
    bf16*  zb  = (bf16*)(wsb + 26936320);           // 16 B zeros
    float* xm  = (float*)(wsb + 26936336);          // 64*256*25*4  =  1,638,400
    float* att = (float*)(wsb + 28574736);          // 64*256*25*4  =  1,638,400

    prep    <<<dim3(2659),       dim3(256), 0, stream>>>(fc_w, dep_w, w1, w2, w3,
                                                         b1, b2, b3, Ap, Vt, zb);
    xpose   <<<dim3(25, 8, 64),  dim3(256), 0, stream>>>(x, xT);
    xmk     <<<dim3(256, 64),    dim3(64),  0, stream>>>(x, xm);
    attg    <<<dim3(64),         dim3(256), 0, stream>>>(xm, w3, b3, att);
    convgemm<<<dim3(7, 2, 64),   dim3(256), 0, stream>>>(Ap, xT, Vt, zb, att,
                                                         rate1, rate2, out);
}

// Round 6
// 255.885 us; speedup vs baseline: 1.3430x; 1.3430x over previous
//
#include <hip/hip_runtime.h>
#include <hip/hip_bf16.h>

typedef __hip_bfloat16 bf16;
typedef unsigned int uint;
typedef unsigned short ushort;

using frag8 = __attribute__((ext_vector_type(8))) short;   // 8 bf16
using f32x4 = __attribute__((ext_vector_type(4))) float;

#define HWH 784   // 28*28

// ---------------------------------------------------------------------------
// Fold fc_w (9x12) into dep_w (256,9,3,3):  W2[oc][c12][k9]; also biascat.
// ---------------------------------------------------------------------------
__global__ __launch_bounds__(256) void fold_w2(const float* __restrict__ fc_w,
                                               const float* __restrict__ dep_w,
                                               const float* __restrict__ b1,
                                               const float* __restrict__ b2,
                                               const float* __restrict__ b3,
                                               float* __restrict__ W2,
                                               float* __restrict__ biascat) {
    int idx = blockIdx.x * 256 + threadIdx.x;   // oc*108 + c12*9 + k9
    if (idx < 768) {
        const float* bs = idx < 256 ? b1 : (idx < 512 ? b2 : b3);
        biascat[idx] = bs[idx & 255];
    }
    if (idx >= 256 * 108) return;
    int oc  = idx / 108;
    int r   = idx % 108;
    int c12 = r / 9;
    int k9  = r % 9;
    float s = 0.f;
#pragma unroll
    for (int o = 0; o < 9; ++o)
        s += fc_w[o * 12 + c12] * dep_w[oc * 81 + o * 9 + k9];
    W2[idx] = s;
}

// ---------------------------------------------------------------------------
// Weights f32 -> bf16, concatenated [768][256] (q:w1, k:w2, v:w3)
// ---------------------------------------------------------------------------
__global__ __launch_bounds__(256) void wprep(const float* __restrict__ w1,
                                             const float* __restrict__ w2,
                                             const float* __restrict__ w3,
                                             bf16* __restrict__ wbf) {
    int row = blockIdx.x, tid = threadIdx.x;
    const float* src = row < 256 ? w1 : (row < 512 ? w2 : w3);
    wbf[row * 256 + tid] = __float2bfloat16(src[(row & 255) * 256 + tid]);
}

// ---------------------------------------------------------------------------
// x [b][c=256][n=784] f32  ->  xT [b][n=784][c=256] bf16  (32x32 LDS tiles)
// ---------------------------------------------------------------------------
__global__ __launch_bounds__(256) void xpose(const float* __restrict__ x,
                                             bf16* __restrict__ xT) {
    __shared__ float t[32][33];
    const int n0 = blockIdx.x * 32, c0 = blockIdx.y * 32, b = blockIdx.z;
    const int tid = threadIdx.x;
    const float* xb = x + (size_t)b * (256 * HWH);
#pragma unroll
    for (int e = tid; e < 1024; e += 256) {
        int r = e >> 5, col = e & 31;           // r: c-index, col: n-index
        int n = n0 + col;
        t[r][col] = (n < HWH) ? xb[(size_t)(c0 + r) * HWH + n] : 0.f;
    }
    __syncthreads();
#pragma unroll
    for (int e = tid; e < 512; e += 256) {
        int r = e >> 4, cp = (e & 15) * 2;      // r: n-index, cp: c-pair
        int n = n0 + r;
        if (n < HWH) {
            __hip_bfloat162 h;
            h.x = __float2bfloat16(t[cp][r]);
            h.y = __float2bfloat16(t[cp + 1][r]);
            *reinterpret_cast<__hip_bfloat162*>(
                &xT[((size_t)b * HWH + n) * 256 + c0 + cp]) = h;
        }
    }
}

// ---------------------------------------------------------------------------
// MFMA GEMM: perm[b][g][t][n] = sum_k wbf[m][k] * xT[b][n][k] + bias[m]
// where m -> sec=m/256, ch=m%256, g=ch%64, head=ch/64, t=sec*4+head.
// (unchanged from R4)
// ---------------------------------------------------------------------------
__device__ inline void load_lds16(const bf16* g, short* lds) {
    __builtin_amdgcn_global_load_lds(
        (const __attribute__((address_space(1))) void*)g,
        (__attribute__((address_space(3))) void*)lds, 16, 0, 0);
}

__global__ __launch_bounds__(256) void gemm_mfma(const bf16* __restrict__ wbf,
                                                 const float* __restrict__ biascat,
                                                 const bf16* __restrict__ xT,
                                                 bf16* __restrict__ perm) {
    __shared__ short lds[8192];                 // A: [0,4096) shorts, B: [4096,8192)

    const int tid  = threadIdx.x;
    const int wave = tid >> 6, lane = tid & 63;
    const int b    = blockIdx.z;
    const int m0   = blockIdx.y * 128;
    const int n0   = blockIdx.x * 128;
    const int mw   = wave & 1, nw = wave >> 1;  // 2x2 wave grid of 64x64 tiles
    const int lrow = lane & 15, lkc = lane >> 4;  // fragment row / k-chunk

    f32x4 acc[4][4] = {};
    const bf16* xb = xT + (size_t)b * (HWH * 256);

    for (int k0 = 0; k0 < 256; k0 += 32) {
#pragma unroll
        for (int i = 0; i < 2; ++i) {
            const int jb = 2 * wave + i;        // fragment-block (16 rows)
            const bf16* ga = wbf + (size_t)(m0 + 16 * jb + lrow) * 256 + k0 + lkc * 8;
            load_lds16(ga, &lds[jb * 512]);
            int n = n0 + 16 * jb + lrow;
            if (n > HWH - 1) n = HWH - 1;       // clamp: OOB cols never stored
            const bf16* gb = xb + (size_t)n * 256 + k0 + lkc * 8;
            load_lds16(gb, &lds[4096 + jb * 512]);
        }
        __syncthreads();

        frag8 af[4], bf_[4];
#pragma unroll
        for (int i = 0; i < 4; ++i)
            af[i] = *reinterpret_cast<const frag8*>(&lds[(4 * mw + i) * 512 + lane * 8]);
#pragma unroll
        for (int j = 0; j < 4; ++j)
            bf_[j] = *reinterpret_cast<const frag8*>(&lds[4096 + (4 * nw + j) * 512 + lane * 8]);
#pragma unroll
        for (int i = 0; i < 4; ++i)
#pragma unroll
            for (int j = 0; j < 4; ++j)
                acc[i][j] = __builtin_amdgcn_mfma_f32_16x16x32_bf16(
                    af[i], bf_[j], acc[i][j], 0, 0, 0);
        __syncthreads();
    }

    // Epilogue: C/D layout col=lane&15 (n), row=(lane>>4)*4+reg (m)
#pragma unroll
    for (int i = 0; i < 4; ++i) {
        const int rowb = m0 + mw * 64 + i * 16 + lkc * 4;
        bf16* dsts[4]; float bias4[4];
#pragma unroll
        for (int r = 0; r < 4; ++r) {
            const int m = rowb + r;
            const int sec = m >> 8, ch = m & 255;
            dsts[r] = perm + (((size_t)b * 64 + (ch & 63)) * 12 + sec * 4 + (ch >> 6)) * HWH;
            bias4[r] = biascat[m];
        }
#pragma unroll
        for (int j = 0; j < 4; ++j) {
            const int col = n0 + nw * 64 + j * 16 + lrow;
            if (col < HWH) {
#pragma unroll
                for (int r = 0; r < 4; ++r)
                    dsts[r][col] = __float2bfloat16(acc[i][j][r] + bias4[r]);
            }
        }
    }
}

// ---------------------------------------------------------------------------
// Fused output: out = rate1 * att + rate2 * conv.
// R6 change: conv planes kept as bf16 in LDS (pitch 34 shorts -> 4B-aligned
// paired reads, lane stride 17 banks => conflict-free). LDS 54 KB -> ~34 KB,
// 2 -> 4 blocks/CU.
// ---------------------------------------------------------------------------
__global__ __launch_bounds__(256) void out_fused4(
    const bf16* __restrict__ perm, const float* __restrict__ W2,
    const float* __restrict__ rate1, const float* __restrict__ rate2,
    float* __restrict__ out) {
    __shared__ __align__(16) short plane[12][1020];  // 30 rows x pitch 34, 1-halo
    __shared__ float w2s2[4][12][12];                // [oc][c][k], k padded 9->12
    __shared__ float attb[4][49];
    __shared__ __align__(16) short vatt[4][784];

    const int g = blockIdx.x, b = blockIdx.y, tid = threadIdx.x;
    const ushort zero_bf = 0;

    // ---- phase A: LDS fill ----
    for (int e = tid; e < 576; e += 256) {      // weights, float4-friendly layout
        int oc = e / 144, rem = e % 144, c = rem / 12, k = rem % 12;
        w2s2[oc][c][k] = (k < 9) ? W2[(4 * g + oc) * 108 + c * 9 + k] : 0.f;
    }
    if (tid < 196) attb[tid / 49][tid % 49] = 0.f;
    for (int e = tid; e < 1392; e += 256) {     // zero halo borders only
        int c12 = e / 116, u = e % 116, idx;
        if (u < 30)      idx = u;                        // top row
        else if (u < 60) idx = 29 * 34 + (u - 30);       // bottom row
        else { int v = u - 60; idx = ((v >> 1) + 1) * 34 + (v & 1) * 29; }
        plane[c12][idx] = (short)zero_bf;
    }
    {   // 12 conv planes: one contiguous 18,816 B streak of uint4 (8 px each)
        const uint4* src = (const uint4*)(perm + ((size_t)b * 64 + g) * 12 * HWH);
        for (int e = tid; e < 1176; e += 256) {
            int c12 = e / 98, u = e % 98;
            uint4 q = src[e];
            ushort s8[8] = {(ushort)(q.x & 0xffff), (ushort)(q.x >> 16),
                            (ushort)(q.y & 0xffff), (ushort)(q.y >> 16),
                            (ushort)(q.z & 0xffff), (ushort)(q.z >> 16),
                            (ushort)(q.w & 0xffff), (ushort)(q.w >> 16)};
            int p = u * 8, y = p / 28, x = p - y * 28;
            int ry = y + 1, cx = x + 1;
            short* pl = &plane[c12][0];
#pragma unroll
            for (int t4 = 0; t4 < 8; ++t4) {
                pl[ry * 34 + cx] = (short)s8[t4];
                if (++cx == 29) { cx = 1; ++ry; }
            }
        }
    }
    for (int e = tid; e < 392; e += 256) {      // 4 v-planes for attention
        int oc = e / 98, u = e % 98;
        int c = 4 * g + oc;                     // v channel -> perm[b][c%64][8+c/64]
        const uint4* src = (const uint4*)(
            perm + (((size_t)b * 64 + (c & 63)) * 12 + 8 + (c >> 6)) * HWH);
        reinterpret_cast<uint4*>(&vatt[oc][0])[u] = src[u];
    }
    __syncthreads();

    // ---- phase B: attention window means (interior windows only) ----
    if (tid < 100) {
        int oc = tid / 25, w = tid % 25;
        int wi = w / 5 + 1, wj = w % 5 + 1;
        int r0 = 4 * wi - 4, c0 = 4 * wj - 4;
        float s = 0.f;
#pragma unroll
        for (int r = 0; r < 12; ++r) {
            const __hip_bfloat162* pv =
                (const __hip_bfloat162*)&vatt[oc][(r0 + r) * 28 + c0];
#pragma unroll
            for (int q = 0; q < 6; ++q) {
                float2 f = __bfloat1622float2(pv[q]);
                s += f.x + f.y;
            }
        }
        attb[oc][wi * 7 + wj] = s * (1.0f / 144.0f);
    }

    // ---- phase C: conv. Lanes consecutive in y, pitch 34 shorts:
    //      bank stride 17 (coprime with 32) -> conflict-free; x0 even -> b32 ok
    float acc[4][4] = {};   // [oc][px]
    const int y = tid % 28, xs = tid / 28, x0 = xs * 4;
    if (tid < 196) {
#pragma unroll
        for (int c = 0; c < 12; ++c) {
            float rr[3][6];
#pragma unroll
            for (int dy = 0; dy < 3; ++dy) {
                const uint* row = (const uint*)&plane[c][(y + dy) * 34 + x0];
#pragma unroll
                for (int jp = 0; jp < 3; ++jp) {
                    uint w = row[jp];
                    float2 f = __bfloat1622float2(*(const __hip_bfloat162*)&w);
                    rr[dy][2 * jp]     = f.x;
                    rr[dy][2 * jp + 1] = f.y;
                }
            }
#pragma unroll
            for (int oc = 0; oc < 4; ++oc) {
                const float4* wr = reinterpret_cast<const float4*>(&w2s2[oc][c][0]);
                float4 wa = wr[0], wb = wr[1], wc = wr[2];
                const float wk[9] = {wa.x, wa.y, wa.z, wa.w, wb.x, wb.y, wb.z, wb.w, wc.x};
#pragma unroll
                for (int ky = 0; ky < 3; ++ky)
#pragma unroll
                    for (int kx = 0; kx < 3; ++kx) {
                        float wv = wk[ky * 3 + kx];
#pragma unroll
                        for (int px = 0; px < 4; ++px)
                            acc[oc][px] += wv * rr[ky][px + kx];
                    }
            }
        }
    }
    __syncthreads();

    // ---- phase D: combine + store ----
    if (tid < 196) {
        const float r1 = rate1[0], r2 = rate2[0];
        const int wi = y >> 2, wj = xs;
#pragma unroll
        for (int oc = 0; oc < 4; ++oc) {
            float av = attb[oc][wi * 7 + wj] * r1;
            float4 o;
            o.x = av + r2 * acc[oc][0];
            o.y = av + r2 * acc[oc][1];
            o.z = av + r2 * acc[oc][2];
            o.w = av + r2 * acc[oc][3];
            *reinterpret_cast<float4*>(
                &out[((size_t)(b * 256 + 4 * g + oc)) * HWH + y * 28 + x0]) = o;
        }
    }
}

// ---------------------------------------------------------------------------
extern "C" void kernel_launch(void* const* d_in, const int* in_sizes, int n_in,
                              void* d_out, int out_size, void* d_ws, size_t ws_size,
                              hipStream_t stream) {
    const float* x     = (const float*)d_in[0];
    const float* w1    = (const float*)d_in[1];
    const float* b1    = (const float*)d_in[2];
    const float* w2    = (const float*)d_in[3];
    const float* b2    = (const float*)d_in[4];
    const float* w3    = (const float*)d_in[5];
    const float* b3    = (const float*)d_in[6];
    const float* fc_w  = (const float*)d_in[7];
    const float* dep_w = (const float*)d_in[8];
    // d_in[9]/d_in[10] = rel_height/rel_width: provably dead (mask collapse)
    const float* rate1 = (const float*)d_in[11];
    const float* rate2 = (const float*)d_in[12];
    float* out = (float*)d_out;

    // workspace layout — identical to the passing R4 build.
    // perm = 64*64*12*784 elements * 2 B = 77,070,336 BYTES.
    char* wsb = (char*)d_ws;
    bf16*  perm    = (bf16*)wsb;                         // 77,070,336 B
    bf16*  xT      = (bf16*)(wsb + 77070336);            // 64*784*256*2 = 25,690,112 B
    bf16*  wbf     = (bf16*)(wsb + 102760448);           // 768*256*2    =    393,216 B
    float* W2      = (float*)(wsb + 103153664);          // 256*108*4    =    110,592 B
    float* biascat = (float*)(wsb + 103264256);          // 768*4        =      3,072 B

    fold_w2  <<<dim3(108),        dim3(256), 0, stream>>>(fc_w, dep_w, b1, b2, b3, W2, biascat);
    wprep    <<<dim3(768),        dim3(256), 0, stream>>>(w1, w2, w3, wbf);
    xpose    <<<dim3(25, 8, 64),  dim3(256), 0, stream>>>(x, xT);
    gemm_mfma<<<dim3(7, 6, 64),   dim3(256), 0, stream>>>(wbf, biascat, xT, perm);
    out_fused4<<<dim3(64, 64),    dim3(256), 0, stream>>>(perm, W2, rate1, rate2, out);
}